// Round 4
// baseline (2123.094 us; speedup 1.0000x reference)
//
#include <hip/hip_runtime.h>

#define HIDDEN 128
#define N_NEG 25
#define NTASK 26          // task 0 = positive, 1..25 = negatives
#define MARGIN 4.0f
#define BATCH 4096

// ws layout: float scores[NTASK][BATCH]  (425,984 B)
//            int   cnt[BATCH]            (16,384 B)

struct TripleRows {
    float2 he, ht, te, tt, re, rt;
};

__device__ __forceinline__ TripleRows load_rows(
    const float* __restrict__ ent,   const float* __restrict__ enttr,
    const float* __restrict__ rel,   const float* __restrict__ reltr,
    int h, int t, int r, int lane)
{
    const size_t ho = (size_t)h * HIDDEN + (size_t)(lane * 2);
    const size_t to = (size_t)t * HIDDEN + (size_t)(lane * 2);
    const size_t ro = (size_t)r * HIDDEN + (size_t)(lane * 2);
    TripleRows x;
    x.he = *reinterpret_cast<const float2*>(ent   + ho);
    x.ht = *reinterpret_cast<const float2*>(enttr + ho);
    x.te = *reinterpret_cast<const float2*>(ent   + to);
    x.tt = *reinterpret_cast<const float2*>(enttr + to);
    x.re = *reinterpret_cast<const float2*>(rel   + ro);
    x.rt = *reinterpret_cast<const float2*>(reltr + ro);
    return x;
}

// When cnt[b] hits NTASK, all 26 scores for b are visible (release->acquire):
// lanes 0..25 read them, shuffle-reduce, one atomicAdd of the hinge loss.
__device__ __forceinline__ void finish_b(
    const float* __restrict__ scores, float* __restrict__ out, int b, int lane)
{
    float v = 0.0f;
    if (lane < NTASK)
        v = __hip_atomic_load(scores + (size_t)lane * BATCH + b,
                              __ATOMIC_RELAXED, __HIP_MEMORY_SCOPE_AGENT);
    const float p = __shfl(v, 0);
    float n = (lane >= 1) ? v : 0.0f;   // lanes >= NTASK contribute 0
    #pragma unroll
    for (int off = 32; off >= 1; off >>= 1) n += __shfl_xor(n, off);
    if (lane == 0)
        atomicAdd(out, fmaxf(p - n * (1.0f / N_NEG) + MARGIN, 0.0f));
}

// Each wave scores TWO triples (12 row loads in flight, interleaved
// reductions), then participates in the fused hinge via completion counters.
__global__ void __launch_bounds__(256)
score_fused_kernel(
    const float* __restrict__ ent,   const float* __restrict__ rel,
    const float* __restrict__ enttr, const float* __restrict__ reltr,
    const int* __restrict__ pos_h, const int* __restrict__ pos_t,
    const int* __restrict__ pos_r,
    const int* __restrict__ neg_h, const int* __restrict__ neg_t,
    const int* __restrict__ neg_r,
    float* __restrict__ scores, int* __restrict__ cnt,
    float* __restrict__ out)
{
    const int lane = threadIdx.x & 63;
    const int w    = blockIdx.x * 4 + (threadIdx.x >> 6);
    const int tri0 = w * 2;
    const int tri1 = tri0 + 1;

    const int b0 = tri0 / NTASK, task0 = tri0 - b0 * NTASK;
    const int b1 = tri1 / NTASK, task1 = tri1 - b1 * NTASK;

    int h0, t0, r0, h1, t1, r1;
    if (task0 == 0) { h0 = pos_h[b0]; t0 = pos_t[b0]; r0 = pos_r[b0]; }
    else { const int j = b0 * N_NEG + (task0 - 1);
           h0 = neg_h[j]; t0 = neg_t[j]; r0 = neg_r[j]; }
    if (task1 == 0) { h1 = pos_h[b1]; t1 = pos_t[b1]; r1 = pos_r[b1]; }
    else { const int j = b1 * N_NEG + (task1 - 1);
           h1 = neg_h[j]; t1 = neg_t[j]; r1 = neg_r[j]; }

    const TripleRows a = load_rows(ent, enttr, rel, reltr, h0, t0, r0, lane);
    const TripleRows c = load_rows(ent, enttr, rel, reltr, h1, t1, r1, lane);

    // diff = dot(h_e,h_t) - dot(t_e,t_t): reduce the per-lane difference once.
    float d0 = a.he.x * a.ht.x + a.he.y * a.ht.y
             - a.te.x * a.tt.x - a.te.y * a.tt.y;
    float d1 = c.he.x * c.ht.x + c.he.y * c.ht.y
             - c.te.x * c.tt.x - c.te.y * c.tt.y;
    #pragma unroll
    for (int off = 32; off >= 1; off >>= 1) {
        d0 += __shfl_xor(d0, off);
        d1 += __shfl_xor(d1, off);
    }

    float s0 = fabsf(a.he.x - a.te.x + a.re.x + d0 * a.rt.x)
             + fabsf(a.he.y - a.te.y + a.re.y + d0 * a.rt.y);
    float s1 = fabsf(c.he.x - c.te.x + c.re.x + d1 * c.rt.x)
             + fabsf(c.he.y - c.te.y + c.re.y + d1 * c.rt.y);
    #pragma unroll
    for (int off = 32; off >= 1; off >>= 1) {
        s0 += __shfl_xor(s0, off);
        s1 += __shfl_xor(s1, off);
    }

    // Publish scores (agent-scope write-through stores, no L2-resident dirty
    // lines -> visible across XCDs), then release via acq_rel counter bump.
    int old0 = 0, old1 = 0;
    if (lane == 0) {
        __hip_atomic_store(scores + (size_t)task0 * BATCH + b0, s0,
                           __ATOMIC_RELAXED, __HIP_MEMORY_SCOPE_AGENT);
        __hip_atomic_store(scores + (size_t)task1 * BATCH + b1, s1,
                           __ATOMIC_RELAXED, __HIP_MEMORY_SCOPE_AGENT);
        old0 = __hip_atomic_fetch_add(&cnt[b0], 1,
                                      __ATOMIC_ACQ_REL, __HIP_MEMORY_SCOPE_AGENT);
        old1 = __hip_atomic_fetch_add(&cnt[b1], 1,
                                      __ATOMIC_ACQ_REL, __HIP_MEMORY_SCOPE_AGENT);
    }
    old0 = __shfl(old0, 0);
    old1 = __shfl(old1, 0);

    if (old0 == NTASK - 1) finish_b(scores, out, b0, lane);
    if (old1 == NTASK - 1) finish_b(scores, out, b1, lane);
}

__global__ void __launch_bounds__(256)
init_kernel(float* __restrict__ out, int* __restrict__ cnt)
{
    const int i = blockIdx.x * 256 + threadIdx.x;
    if (i < BATCH) cnt[i] = 0;
    if (i == 0) out[0] = 0.0f;
}

extern "C" void kernel_launch(void* const* d_in, const int* in_sizes, int n_in,
                              void* d_out, int out_size, void* d_ws, size_t ws_size,
                              hipStream_t stream)
{
    const float* ent   = (const float*)d_in[0];  // ent_embeddings [1M,128]
    const float* rel   = (const float*)d_in[1];  // rel_embeddings [1000,128]
    const float* enttr = (const float*)d_in[2];  // ent_transfer   [1M,128]
    const float* reltr = (const float*)d_in[3];  // rel_transfer   [1000,128]
    const int* pos_h = (const int*)d_in[4];
    const int* pos_t = (const int*)d_in[5];
    const int* pos_r = (const int*)d_in[6];
    const int* neg_h = (const int*)d_in[7];
    const int* neg_t = (const int*)d_in[8];
    const int* neg_r = (const int*)d_in[9];
    float* out    = (float*)d_out;
    float* scores = (float*)d_ws;
    int*   cnt    = (int*)((char*)d_ws + (size_t)NTASK * BATCH * sizeof(float));

    init_kernel<<<(BATCH + 255) / 256, 256, 0, stream>>>(out, cnt);

    // 4096*26 triples, two per wave, 4 waves per block -> 13312 blocks.
    score_fused_kernel<<<(BATCH * NTASK) / 8, 256, 0, stream>>>(
        ent, rel, enttr, reltr,
        pos_h, pos_t, pos_r, neg_h, neg_t, neg_r,
        scores, cnt, out);
}

// Round 5
// 66.584 us; speedup vs baseline: 31.8862x; 31.8862x over previous
//
#include <hip/hip_runtime.h>

#define HIDDEN 128
#define N_NEG 25
#define NTASK 26          // task 0 = positive, 1..25 = negatives
#define MARGIN 4.0f
#define BATCH 4096

struct TripleRows {
    float2 he, ht, te, tt, re, rt;
};

__device__ __forceinline__ TripleRows load_rows(
    const float* __restrict__ ent,   const float* __restrict__ enttr,
    const float* __restrict__ rel,   const float* __restrict__ reltr,
    int h, int t, int r, int lane)
{
    const size_t ho = (size_t)h * HIDDEN + (size_t)(lane * 2);
    const size_t to = (size_t)t * HIDDEN + (size_t)(lane * 2);
    const size_t ro = (size_t)r * HIDDEN + (size_t)(lane * 2);
    TripleRows x;
    x.he = *reinterpret_cast<const float2*>(ent   + ho);
    x.ht = *reinterpret_cast<const float2*>(enttr + ho);
    x.te = *reinterpret_cast<const float2*>(ent   + to);
    x.tt = *reinterpret_cast<const float2*>(enttr + to);
    x.re = *reinterpret_cast<const float2*>(rel   + ro);
    x.rt = *reinterpret_cast<const float2*>(reltr + ro);
    return x;
}

// Each wave scores TWO triples: 12 independent 512B row loads in flight,
// two shuffle-reduction chains interleaved for ILP. Plain cached stores of
// the per-triple scores to ws (visibility via inter-kernel drain, NOT
// in-kernel coherence -- R4 showed agent-scope sync in the gather kernel
// costs 40x).
__global__ void __launch_bounds__(256)
score_kernel(const float* __restrict__ ent,   const float* __restrict__ rel,
             const float* __restrict__ enttr, const float* __restrict__ reltr,
             const int* __restrict__ pos_h, const int* __restrict__ pos_t,
             const int* __restrict__ pos_r,
             const int* __restrict__ neg_h, const int* __restrict__ neg_t,
             const int* __restrict__ neg_r,
             float* __restrict__ scores)       // [NTASK][BATCH]
{
    const int lane = threadIdx.x & 63;
    const int w    = blockIdx.x * 4 + (threadIdx.x >> 6);  // global wave id
    const int tri0 = w * 2;
    const int tri1 = tri0 + 1;

    const int b0 = tri0 / NTASK, task0 = tri0 - b0 * NTASK;
    const int b1 = tri1 / NTASK, task1 = tri1 - b1 * NTASK;

    int h0, t0, r0, h1, t1, r1;
    if (task0 == 0) { h0 = pos_h[b0]; t0 = pos_t[b0]; r0 = pos_r[b0]; }
    else { const int j = b0 * N_NEG + (task0 - 1);
           h0 = neg_h[j]; t0 = neg_t[j]; r0 = neg_r[j]; }
    if (task1 == 0) { h1 = pos_h[b1]; t1 = pos_t[b1]; r1 = pos_r[b1]; }
    else { const int j = b1 * N_NEG + (task1 - 1);
           h1 = neg_h[j]; t1 = neg_t[j]; r1 = neg_r[j]; }

    const TripleRows a = load_rows(ent, enttr, rel, reltr, h0, t0, r0, lane);
    const TripleRows c = load_rows(ent, enttr, rel, reltr, h1, t1, r1, lane);

    // diff = dot(h_e,h_t) - dot(t_e,t_t): reduce the per-lane difference once.
    float d0 = a.he.x * a.ht.x + a.he.y * a.ht.y
             - a.te.x * a.tt.x - a.te.y * a.tt.y;
    float d1 = c.he.x * c.ht.x + c.he.y * c.ht.y
             - c.te.x * c.tt.x - c.te.y * c.tt.y;
    #pragma unroll
    for (int off = 32; off >= 1; off >>= 1) {
        d0 += __shfl_xor(d0, off);
        d1 += __shfl_xor(d1, off);
    }

    // s[d] = | h_e[d] - t_e[d] + r_e[d] + diff * r_t[d] |
    float s0 = fabsf(a.he.x - a.te.x + a.re.x + d0 * a.rt.x)
             + fabsf(a.he.y - a.te.y + a.re.y + d0 * a.rt.y);
    float s1 = fabsf(c.he.x - c.te.x + c.re.x + d1 * c.rt.x)
             + fabsf(c.he.y - c.te.y + c.re.y + d1 * c.rt.y);
    #pragma unroll
    for (int off = 32; off >= 1; off >>= 1) {
        s0 += __shfl_xor(s0, off);
        s1 += __shfl_xor(s1, off);
    }

    if (lane == 0) {
        scores[(size_t)task0 * BATCH + b0] = s0;
        scores[(size_t)task1 * BATCH + b1] = s1;
    }
}

// Single 1024-thread block: each thread handles 4 batch items, computes the
// hinge, block-reduces via LDS, writes out[0] directly. No atomics, no
// zero-init kernel needed.
__global__ void __launch_bounds__(1024)
loss_kernel(const float* __restrict__ scores, float* __restrict__ out)
{
    float acc = 0.0f;
    #pragma unroll
    for (int it = 0; it < BATCH / 1024; ++it) {
        const int b = it * 1024 + threadIdx.x;
        const float p = scores[b];             // task 0 row
        float n = 0.0f;
        #pragma unroll
        for (int k = 1; k < NTASK; ++k) n += scores[(size_t)k * BATCH + b];
        acc += fmaxf(p - n * (1.0f / N_NEG) + MARGIN, 0.0f);
    }

    #pragma unroll
    for (int off = 32; off >= 1; off >>= 1) acc += __shfl_xor(acc, off);

    __shared__ float sh[16];
    if ((threadIdx.x & 63) == 0) sh[threadIdx.x >> 6] = acc;
    __syncthreads();
    if (threadIdx.x < 64) {
        float v = (threadIdx.x < 16) ? sh[threadIdx.x] : 0.0f;
        #pragma unroll
        for (int off = 8; off >= 1; off >>= 1) v += __shfl_xor(v, off);
        if (threadIdx.x == 0) out[0] = v;
    }
}

extern "C" void kernel_launch(void* const* d_in, const int* in_sizes, int n_in,
                              void* d_out, int out_size, void* d_ws, size_t ws_size,
                              hipStream_t stream)
{
    const float* ent   = (const float*)d_in[0];  // ent_embeddings [1M,128]
    const float* rel   = (const float*)d_in[1];  // rel_embeddings [1000,128]
    const float* enttr = (const float*)d_in[2];  // ent_transfer   [1M,128]
    const float* reltr = (const float*)d_in[3];  // rel_transfer   [1000,128]
    const int* pos_h = (const int*)d_in[4];
    const int* pos_t = (const int*)d_in[5];
    const int* pos_r = (const int*)d_in[6];
    const int* neg_h = (const int*)d_in[7];
    const int* neg_t = (const int*)d_in[8];
    const int* neg_r = (const int*)d_in[9];
    float* out    = (float*)d_out;
    float* scores = (float*)d_ws;               // NTASK*BATCH floats = 426 KB

    // 4096*26 triples, two per wave, 4 waves per block -> 13312 blocks.
    score_kernel<<<(BATCH * NTASK) / 8, 256, 0, stream>>>(
        ent, rel, enttr, reltr,
        pos_h, pos_t, pos_r, neg_h, neg_t, neg_r, scores);

    loss_kernel<<<1, 1024, 0, stream>>>(scores, out);
}

// Round 6
// 47.688 us; speedup vs baseline: 44.5206x; 1.3962x over previous
//
#include <hip/hip_runtime.h>

#define HIDDEN 128
#define N_NEG 25
#define NTASK 26          // task 0 = positive, 1..25 = negatives
#define MARGIN 4.0f
#define BATCH 4096

// Half-wave per triple: lanes 0-31 own triple A, lanes 32-63 own triple B.
// Each lane holds float4 (16B) -> one global_load_dwordx4 fetches BOTH
// triples' 512B rows (2x fewer load instrs than float2/full-wave), and the
// xor-butterfly with offsets 16..1 stays inside each 32-lane half, so ONE
// 5-step shuffle chain reduces both triples simultaneously (2.4x fewer
// cross-lane ops). R4 lesson: no agent-scope sync in the gather kernel.
__global__ void __launch_bounds__(256)
score_kernel(const float* __restrict__ ent,   const float* __restrict__ rel,
             const float* __restrict__ enttr, const float* __restrict__ reltr,
             const int* __restrict__ pos_h, const int* __restrict__ pos_t,
             const int* __restrict__ pos_r,
             const int* __restrict__ neg_h, const int* __restrict__ neg_t,
             const int* __restrict__ neg_r,
             float* __restrict__ scores)       // [NTASK][BATCH]
{
    const int lane = threadIdx.x & 63;
    const int sub  = lane & 31;               // quad index within the row
    const int hi   = lane >> 5;               // which triple of the pair
    const int w    = blockIdx.x * 4 + (threadIdx.x >> 6);
    const int tri  = w * 2 + hi;

    const int b    = tri / NTASK;
    const int task = tri - b * NTASK;

    const int jneg = b * N_NEG + (task - 1);  // only read when task > 0
    const int h = (task == 0) ? pos_h[b] : neg_h[jneg];
    const int t = (task == 0) ? pos_t[b] : neg_t[jneg];
    const int r = (task == 0) ? pos_r[b] : neg_r[jneg];

    const size_t ho = (size_t)h * HIDDEN + (size_t)(sub * 4);
    const size_t to = (size_t)t * HIDDEN + (size_t)(sub * 4);
    const size_t ro = (size_t)r * HIDDEN + (size_t)(sub * 4);

    const float4 he = *reinterpret_cast<const float4*>(ent   + ho);
    const float4 ht = *reinterpret_cast<const float4*>(enttr + ho);
    const float4 te = *reinterpret_cast<const float4*>(ent   + to);
    const float4 tt = *reinterpret_cast<const float4*>(enttr + to);
    const float4 re = *reinterpret_cast<const float4*>(rel   + ro);
    const float4 rt = *reinterpret_cast<const float4*>(reltr + ro);

    // diff = dot(h_e,h_t) - dot(t_e,t_t), reduced across the 32-lane half.
    float d = he.x * ht.x + he.y * ht.y + he.z * ht.z + he.w * ht.w
            - te.x * tt.x - te.y * tt.y - te.z * tt.z - te.w * tt.w;
    #pragma unroll
    for (int off = 16; off >= 1; off >>= 1) d += __shfl_xor(d, off);

    // s[j] = | h_e[j] - t_e[j] + r_e[j] + d * r_t[j] |
    float s = fabsf(he.x - te.x + re.x + d * rt.x)
            + fabsf(he.y - te.y + re.y + d * rt.y)
            + fabsf(he.z - te.z + re.z + d * rt.z)
            + fabsf(he.w - te.w + re.w + d * rt.w);
    #pragma unroll
    for (int off = 16; off >= 1; off >>= 1) s += __shfl_xor(s, off);

    if (sub == 0) scores[(size_t)task * BATCH + b] = s;
}

// R3's measured-good loss structure: one thread per batch item, 16 blocks,
// shuffle+LDS reduce, one atomicAdd per block. (R5 showed a single-block
// version is latency-bound on one CU: +18us. Keep this.)
__global__ void __launch_bounds__(256)
loss_kernel(const float* __restrict__ scores, float* __restrict__ out)
{
    const int b = blockIdx.x * 256 + threadIdx.x;

    const float p = scores[b];                 // task 0 row
    float n = 0.0f;
    #pragma unroll
    for (int k = 1; k < NTASK; ++k) n += scores[(size_t)k * BATCH + b];

    float loss = fmaxf(p - n * (1.0f / N_NEG) + MARGIN, 0.0f);

    #pragma unroll
    for (int off = 32; off >= 1; off >>= 1) loss += __shfl_xor(loss, off);

    __shared__ float sh[4];
    if ((threadIdx.x & 63) == 0) sh[threadIdx.x >> 6] = loss;
    __syncthreads();
    if (threadIdx.x == 0)
        atomicAdd(out, sh[0] + sh[1] + sh[2] + sh[3]);
}

__global__ void zero_out_kernel(float* out)
{
    if (threadIdx.x == 0 && blockIdx.x == 0) out[0] = 0.0f;
}

extern "C" void kernel_launch(void* const* d_in, const int* in_sizes, int n_in,
                              void* d_out, int out_size, void* d_ws, size_t ws_size,
                              hipStream_t stream)
{
    const float* ent   = (const float*)d_in[0];  // ent_embeddings [1M,128]
    const float* rel   = (const float*)d_in[1];  // rel_embeddings [1000,128]
    const float* enttr = (const float*)d_in[2];  // ent_transfer   [1M,128]
    const float* reltr = (const float*)d_in[3];  // rel_transfer   [1000,128]
    const int* pos_h = (const int*)d_in[4];
    const int* pos_t = (const int*)d_in[5];
    const int* pos_r = (const int*)d_in[6];
    const int* neg_h = (const int*)d_in[7];
    const int* neg_t = (const int*)d_in[8];
    const int* neg_r = (const int*)d_in[9];
    float* out    = (float*)d_out;
    float* scores = (float*)d_ws;               // NTASK*BATCH floats = 426 KB

    zero_out_kernel<<<1, 64, 0, stream>>>(out);

    // 4096*26 triples, 2 per wave (one per half-wave), 4 waves/block.
    score_kernel<<<(BATCH * NTASK) / 8, 256, 0, stream>>>(
        ent, rel, enttr, reltr,
        pos_h, pos_t, pos_r, neg_h, neg_t, neg_r, scores);

    loss_kernel<<<BATCH / 256, 256, 0, stream>>>(scores, out);
}

// Round 7
// 43.315 us; speedup vs baseline: 49.0150x; 1.1010x over previous
//
#include <hip/hip_runtime.h>

#define HIDDEN 128
#define N_NEG 25
#define NTASK 26          // task 0 = positive, 1..25 = negatives
#define MARGIN 4.0f
#define BATCH 4096

// Half-wave per triple: lanes 0-31 own triple A, lanes 32-63 triple B.
// float4/lane -> one dwordx4 wave-instruction covers both triples' 512B rows;
// xor-butterfly offsets 16..1 stay within each half -> one 5-step shuffle
// chain reduces both triples. Measured (R3/R6): neither more MLP nor fewer
// instructions moves this kernel -- it sits at the ~2.9 TB/s random-512B-
// gather ceiling (DRAM page-opens + per-CU miss-queue concurrency).
__global__ void __launch_bounds__(256, 8)
score_kernel(const float* __restrict__ ent,   const float* __restrict__ rel,
             const float* __restrict__ enttr, const float* __restrict__ reltr,
             const int* __restrict__ pos_h, const int* __restrict__ pos_t,
             const int* __restrict__ pos_r,
             const int* __restrict__ neg_h, const int* __restrict__ neg_t,
             const int* __restrict__ neg_r,
             float* __restrict__ scores,       // [NTASK][BATCH]
             float* __restrict__ out)
{
    // Fold the out-zeroing into this kernel (saves a launch): only the loss
    // kernel (which runs after this one fully drains) reads/writes out.
    if (blockIdx.x == 0 && threadIdx.x == 0) out[0] = 0.0f;

    const int lane = threadIdx.x & 63;
    const int sub  = lane & 31;               // quad index within the row
    const int hi   = lane >> 5;               // which triple of the pair
    const int w    = blockIdx.x * 4 + (threadIdx.x >> 6);
    const int tri  = w * 2 + hi;

    const int b    = tri / NTASK;
    const int task = tri - b * NTASK;

    const int jneg = b * N_NEG + (task - 1);  // only read when task > 0
    const int h = (task == 0) ? pos_h[b] : neg_h[jneg];
    const int t = (task == 0) ? pos_t[b] : neg_t[jneg];
    const int r = (task == 0) ? pos_r[b] : neg_r[jneg];

    const size_t ho = (size_t)h * HIDDEN + (size_t)(sub * 4);
    const size_t to = (size_t)t * HIDDEN + (size_t)(sub * 4);
    const size_t ro = (size_t)r * HIDDEN + (size_t)(sub * 4);

    const float4 he = *reinterpret_cast<const float4*>(ent   + ho);
    const float4 ht = *reinterpret_cast<const float4*>(enttr + ho);
    const float4 te = *reinterpret_cast<const float4*>(ent   + to);
    const float4 tt = *reinterpret_cast<const float4*>(enttr + to);
    const float4 re = *reinterpret_cast<const float4*>(rel   + ro);
    const float4 rt = *reinterpret_cast<const float4*>(reltr + ro);

    // diff = dot(h_e,h_t) - dot(t_e,t_t), reduced across the 32-lane half.
    float d = he.x * ht.x + he.y * ht.y + he.z * ht.z + he.w * ht.w
            - te.x * tt.x - te.y * tt.y - te.z * tt.z - te.w * tt.w;
    #pragma unroll
    for (int off = 16; off >= 1; off >>= 1) d += __shfl_xor(d, off);

    // s[j] = | h_e[j] - t_e[j] + r_e[j] + d * r_t[j] |
    float s = fabsf(he.x - te.x + re.x + d * rt.x)
            + fabsf(he.y - te.y + re.y + d * rt.y)
            + fabsf(he.z - te.z + re.z + d * rt.z)
            + fabsf(he.w - te.w + re.w + d * rt.w);
    #pragma unroll
    for (int off = 16; off >= 1; off >>= 1) s += __shfl_xor(s, off);

    if (sub == 0) scores[(size_t)task * BATCH + b] = s;
}

// R3's measured-good loss structure: one thread per batch item, 16 blocks,
// shuffle+LDS reduce, one atomicAdd per block. (R5: single-block variant is
// latency-bound on one CU, +18us. Keep 16 blocks.)
__global__ void __launch_bounds__(256)
loss_kernel(const float* __restrict__ scores, float* __restrict__ out)
{
    const int b = blockIdx.x * 256 + threadIdx.x;

    const float p = scores[b];                 // task 0 row
    float n = 0.0f;
    #pragma unroll
    for (int k = 1; k < NTASK; ++k) n += scores[(size_t)k * BATCH + b];

    float loss = fmaxf(p - n * (1.0f / N_NEG) + MARGIN, 0.0f);

    #pragma unroll
    for (int off = 32; off >= 1; off >>= 1) loss += __shfl_xor(loss, off);

    __shared__ float sh[4];
    if ((threadIdx.x & 63) == 0) sh[threadIdx.x >> 6] = loss;
    __syncthreads();
    if (threadIdx.x == 0)
        atomicAdd(out, sh[0] + sh[1] + sh[2] + sh[3]);
}

extern "C" void kernel_launch(void* const* d_in, const int* in_sizes, int n_in,
                              void* d_out, int out_size, void* d_ws, size_t ws_size,
                              hipStream_t stream)
{
    const float* ent   = (const float*)d_in[0];  // ent_embeddings [1M,128]
    const float* rel   = (const float*)d_in[1];  // rel_embeddings [1000,128]
    const float* enttr = (const float*)d_in[2];  // ent_transfer   [1M,128]
    const float* reltr = (const float*)d_in[3];  // rel_transfer   [1000,128]
    const int* pos_h = (const int*)d_in[4];
    const int* pos_t = (const int*)d_in[5];
    const int* pos_r = (const int*)d_in[6];
    const int* neg_h = (const int*)d_in[7];
    const int* neg_t = (const int*)d_in[8];
    const int* neg_r = (const int*)d_in[9];
    float* out    = (float*)d_out;
    float* scores = (float*)d_ws;               // NTASK*BATCH floats = 426 KB

    // 4096*26 triples, 2 per wave (one per half-wave), 4 waves/block.
    score_kernel<<<(BATCH * NTASK) / 8, 256, 0, stream>>>(
        ent, rel, enttr, reltr,
        pos_h, pos_t, pos_r, neg_h, neg_t, neg_r, scores, out);

    loss_kernel<<<BATCH / 256, 256, 0, stream>>>(scores, out);
}